// Round 14
// baseline (624.522 us; speedup 1.0000x reference)
//
#include <hip/hip_runtime.h>

// ---------------------------------------------------------------------------
// Sparse 3D U-Net, round 14: r12 skeleton + TRANSPOSED inv table.
//   inv_T[o][28] (112B rows, 27 used + 1 pad): conv1 reads 7x int4 coalesced;
//   reduce's iv-load phase becomes consecutive-address; fill is linear.
//   Scatter side unchanged (scattered 4B writes, same as before).
// ---------------------------------------------------------------------------

#define CDIV(a, b) (((a) + (b)-1) / (b))

typedef __attribute__((ext_vector_type(8))) short bf16x8;
typedef __attribute__((ext_vector_type(4))) float f32x4;

__device__ __forceinline__ unsigned short f2bf(float f) {
  union { float f; unsigned int u; } x{f};
  const unsigned int r = x.u + 0x7fffu + ((x.u >> 16) & 1u);
  return (unsigned short)(r >> 16);
}
__device__ __forceinline__ float bf2f(unsigned short h) {
  union { unsigned int u; float f; } x{(unsigned int)h << 16};
  return x.f;
}
__device__ __forceinline__ unsigned int pk2(float a, float b) {
  return (unsigned int)f2bf(a) | ((unsigned int)f2bf(b) << 16);
}

// linear fill of inv_T rows [0,n): 28n ints = -1
__global__ void fillT_k(int* __restrict__ invT, const int* __restrict__ ndev, int nhost) {
  const int n = (nhost >= 0) ? nhost : __ldg(ndev);
  const long total = (long)n * 28;
  const long i = (long)blockIdx.x * 256 + threadIdx.x;
  if (i < total) invT[i] = -1;
}

// all 6 pgemm-layer kmaps in one launch; base7[L*32 + 0..27]
__global__ void kmap_all_k(const int* __restrict__ m2o, int P2, const int* __restrict__ n1d,
                           const int* __restrict__ m3o, int P3, const int* __restrict__ n2d,
                           const int* __restrict__ m4o, int P4, const int* __restrict__ n3d,
                           const int* __restrict__ m4i, const int* __restrict__ m3i,
                           const int* __restrict__ m2i, int N0, int* __restrict__ base7) {
  const int L = blockIdx.x;
  const int* om; int P, n;
  switch (L) {
    case 0: om = m2o; P = P2; n = __ldg(n1d); break;
    case 1: om = m3o; P = P3; n = __ldg(n2d); break;
    case 2: om = m4o; P = P4; n = __ldg(n3d); break;
    case 3: om = m4i; P = P4; n = __ldg(n2d); break;
    case 4: om = m3i; P = P3; n = __ldg(n1d); break;
    default: om = m2i; P = P2; n = N0; break;
  }
  __shared__ int cnt[27];
  const int k = threadIdx.x;
  if (k < 27) {
    const int* __restrict__ row = om + (long)k * P;
    int lo = 0, hi = P;
    while (lo < hi) {
      const int mid = (lo + hi) >> 1;
      if (row[mid] < n) lo = mid + 1; else hi = mid;
    }
    cnt[k] = lo;
  }
  __syncthreads();
  if (threadIdx.x == 0) {
    int acc = 0;
    int* b = base7 + L * 32;
    for (int j = 0; j < 27; ++j) { b[j] = acc; acc += cnt[j]; }
    b[27] = acc;
  }
}

// inv_T[om[k][p]*28 + k] = base[k] + p
__global__ void inv_scatter_k(const int* __restrict__ om, int P,
                              const int* __restrict__ base,
                              int* __restrict__ invT) {
  const int k = blockIdx.y;
  const int b0 = base[k];
  const int cnt = base[k + 1] - b0;
  const int p0 = blockIdx.x * 256;
  if (p0 >= cnt) return;
  const int p = p0 + threadIdx.x;
  if (p < cnt) invT[(size_t)om[(long)k * P + p] * 28 + k] = b0 + p;
}

// inv_T[om[k][p]*28 + k] = im[k][p] for valid pairs (conv1 path)
__global__ void inv_build_k(const int* __restrict__ im, const int* __restrict__ om,
                            int P, int n, int* __restrict__ invT) {
  const int k = blockIdx.y;
  const int p = blockIdx.x * 256 + threadIdx.x;
  if (p >= P) return;
  const int o = om[(long)k * P + p];
  if (o < n) invT[(size_t)o * 28 + k] = im[(long)k * P + p];
}

// batched weight prep: all 6 W tensors -> frag-ordered bf16, one launch
struct PrepArgs {
  const float* src[6];
  unsigned short* dst[6];
  int cin[6], cout[6], cstart[7];
};
__global__ __launch_bounds__(256) void prep_all_k(PrepArgs pa) {
  const int c = blockIdx.x * 4 + (threadIdx.x >> 6);
  if (c >= pa.cstart[6]) return;
  int ws = 0;
  while (c >= pa.cstart[ws + 1]) ++ws;
  const int local = c - pa.cstart[ws];
  const int CIN = pa.cin[ws], COUT = pa.cout[ws];
  const int NCC = COUT >> 4, NKK = CIN >> 5;
  const int cc = local % NCC;
  const int kk = (local / NCC) % NKK;
  const int k = local / (NCC * NKK);
  const int l = threadIdx.x & 63;
  const float* __restrict__ src =
      pa.src[ws] + ((size_t)k * CIN + kk * 32 + (l >> 4) * 8) * COUT + cc * 16 + (l & 15);
  unsigned short* __restrict__ dst = pa.dst[ws] + (size_t)local * 512 + l * 8;
#pragma unroll
  for (int j = 0; j < 8; ++j) dst[j] = f2bf(src[(size_t)j * COUT]);
}

// Phase 1: compact per-offset pair GEMM (optional column split via cb).
template <int CIN1, int CIN2, int COUT, int NCB, int ARM>
__global__ __launch_bounds__(256) void pgemm_k(
    const unsigned short* __restrict__ actA, const unsigned short* __restrict__ actB,
    const unsigned short* __restrict__ Wf, const int* __restrict__ im, int P,
    const int* __restrict__ base, unsigned short* __restrict__ contrib,
    int cb, int cstride) {
  constexpr int CIN = CIN1 + CIN2;
  constexpr int NKK = CIN / 32;
  constexpr int NCCt = COUT / 16;
  constexpr int NCCb = NCCt / NCB;
  constexpr int T = NKK * NCCb;
  constexpr int SPAN = 4 * ARM * 16;
  __shared__ unsigned short wl[T * 512];

  const int k = blockIdx.y;
  const int b0 = base[k];
  const int cnt = base[k + 1] - b0;
  if ((int)blockIdx.x * SPAN >= cnt) return;

  const int w = threadIdx.x >> 6;
  const int l = threadIdx.x & 63;
  for (int t = w; t < T; t += 4) {
    const int kk_ = t / NCCb, ccl_ = t - kk_ * NCCb;
    const unsigned short* src =
        Wf + (((size_t)k * NKK + kk_) * NCCt + cb * NCCb + ccl_) * 512 + l * 8;
    __builtin_amdgcn_global_load_lds(
        (const __attribute__((address_space(1))) unsigned int*)src,
        (__attribute__((address_space(3))) unsigned int*)(wl + t * 512), 16, 0, 0);
  }
  __syncthreads();  // W staged

  const int lrow = l & 15, lgrp = l >> 4;
  const int t0 = blockIdx.x * SPAN + w * (ARM * 16);

  bf16x8 a[ARM][NKK];
#pragma unroll
  for (int rm = 0; rm < ARM; ++rm) {
    const int p = t0 + rm * 16 + lrow;
    const int iv = (p < cnt) ? im[(size_t)k * P + p] : -1;
#pragma unroll
    for (int kk = 0; kk < NKK; ++kk) {
      if (iv >= 0) {
        const int cbs = kk * 32 + lgrp * 8;
        a[rm][kk] = (CIN2 == 0 || cbs < CIN1)
            ? *reinterpret_cast<const bf16x8*>(actA + (size_t)iv * CIN1 + cbs)
            : *reinterpret_cast<const bf16x8*>(actB + (size_t)iv * CIN2 + (cbs - CIN1));
      } else {
        a[rm][kk] = (bf16x8){0, 0, 0, 0, 0, 0, 0, 0};
      }
    }
  }

  f32x4 acc[ARM][NCCb];
#pragma unroll
  for (int rm = 0; rm < ARM; ++rm)
#pragma unroll
    for (int cc = 0; cc < NCCb; ++cc) acc[rm][cc] = (f32x4){0.f, 0.f, 0.f, 0.f};

#pragma unroll
  for (int kk = 0; kk < NKK; ++kk)
#pragma unroll
    for (int cc = 0; cc < NCCb; ++cc) {
      const bf16x8 b =
          *reinterpret_cast<const bf16x8*>(wl + ((kk * NCCb + cc) * 64 + l) * 8);
#pragma unroll
      for (int rm = 0; rm < ARM; ++rm)
        acc[rm][cc] = __builtin_amdgcn_mfma_f32_16x16x32_bf16(a[rm][kk], b, acc[rm][cc], 0, 0, 0);
    }

#pragma unroll
  for (int rm = 0; rm < ARM; ++rm)
#pragma unroll
    for (int cc = 0; cc < NCCb; ++cc)
#pragma unroll
      for (int r = 0; r < 4; ++r) {
        const int p = t0 + rm * 16 + lgrp * 4 + r;
        if (p < cnt)
          contrib[(size_t)(b0 + p) * cstride + cc * 16 + lrow] = f2bf(acc[rm][cc][r]);
      }
}

// Phase 2: out[o, coff:+COLS] = sum_k contrib[inv_T[o][k]]  (coalesced iv load)
template <int COLS>
__global__ __launch_bounds__(256) void reduce_bf16_k(
    const unsigned short* __restrict__ contrib, const int* __restrict__ invT,
    const int* __restrict__ ndev, int nhost, unsigned short* __restrict__ out,
    int ldo, int coff) {
  constexpr int TPR = COLS / 8;
  constexpr int RPB = 256 / TPR;
  const int n = (nhost >= 0) ? nhost : __ldg(ndev);
  const int r0 = blockIdx.x * RPB;
  if (r0 >= n) return;
  __shared__ int iv[RPB][28];
  for (int i = threadIdx.x; i < RPB * 28; i += 256) {
    const int r = i / 28, k = i - r * 28;
    iv[r][k] = (r0 + r < n && k < 27) ? invT[(size_t)(r0 + r) * 28 + k] : -1;
  }
  __syncthreads();
  const int r = threadIdx.x / TPR;
  const int c8 = (threadIdx.x % TPR) * 8;
  if (r0 + r >= n) return;
  float s[8] = {0.f, 0.f, 0.f, 0.f, 0.f, 0.f, 0.f, 0.f};
#pragma unroll
  for (int k = 0; k < 27; ++k) {
    const int p = iv[r][k];
    if (p >= 0) {
      const bf16x8 v = *reinterpret_cast<const bf16x8*>(contrib + (size_t)p * COLS + c8);
#pragma unroll
      for (int j = 0; j < 8; ++j) s[j] += bf2f((unsigned short)v[j]);
    }
  }
  bf16x8 o;
#pragma unroll
  for (int j = 0; j < 8; ++j) o[j] = (short)f2bf(s[j]);
  *reinterpret_cast<bf16x8*>(out + (size_t)(r0 + r) * ldo + coff + c8) = o;
}

// conv1: thread-per-row; inv row read as 7x int4 (coalesced 112B/row).
__global__ __launch_bounds__(256) void conv1_k(
    const float* __restrict__ feats, const float* __restrict__ W1,
    const int* __restrict__ invT, int n0, unsigned short* __restrict__ e1) {
  __shared__ float w[27 * 128];
  for (int i = threadIdx.x; i < 27 * 128; i += 256) w[i] = W1[i];
  __syncthreads();
  const int r = blockIdx.x * 256 + threadIdx.x;
  if (r >= n0) return;
  int ivk[28];
  const int4* __restrict__ ivsrc = reinterpret_cast<const int4*>(invT + (size_t)r * 28);
#pragma unroll
  for (int j = 0; j < 7; ++j) {
    const int4 v = ivsrc[j];
    ivk[j * 4 + 0] = v.x; ivk[j * 4 + 1] = v.y; ivk[j * 4 + 2] = v.z; ivk[j * 4 + 3] = v.w;
  }
  float4 acc[8];
#pragma unroll
  for (int q = 0; q < 8; ++q) acc[q] = make_float4(0.f, 0.f, 0.f, 0.f);
#pragma unroll
  for (int k = 0; k < 27; ++k) {
    const int iv = ivk[k];
    if (iv < 0) continue;
    const float4 f = *reinterpret_cast<const float4*>(feats + (size_t)iv * 4);
    const float4* __restrict__ wr = reinterpret_cast<const float4*>(&w[k * 128]);
#pragma unroll
    for (int q = 0; q < 8; ++q) {
      const float4 w0 = wr[q], w1 = wr[8 + q], w2 = wr[16 + q], w3 = wr[24 + q];
      acc[q].x += f.x * w0.x + f.y * w1.x + f.z * w2.x + f.w * w3.x;
      acc[q].y += f.x * w0.y + f.y * w1.y + f.z * w2.y + f.w * w3.y;
      acc[q].z += f.x * w0.z + f.y * w1.z + f.z * w2.z + f.w * w3.z;
      acc[q].w += f.x * w0.w + f.y * w1.w + f.z * w2.w + f.w * w3.w;
    }
  }
  uint4* dst = reinterpret_cast<uint4*>(e1 + (size_t)r * 32);
  dst[0] = make_uint4(pk2(acc[0].x, acc[0].y), pk2(acc[0].z, acc[0].w),
                      pk2(acc[1].x, acc[1].y), pk2(acc[1].z, acc[1].w));
  dst[1] = make_uint4(pk2(acc[2].x, acc[2].y), pk2(acc[2].z, acc[2].w),
                      pk2(acc[3].x, acc[3].y), pk2(acc[3].z, acc[3].w));
  dst[2] = make_uint4(pk2(acc[4].x, acc[4].y), pk2(acc[4].z, acc[4].w),
                      pk2(acc[5].x, acc[5].y), pk2(acc[5].z, acc[5].w));
  dst[3] = make_uint4(pk2(acc[6].x, acc[6].y), pk2(acc[6].z, acc[6].w),
                      pk2(acc[7].x, acc[7].y), pk2(acc[7].z, acc[7].w));
}

// ---- BN (grid-stride stats + fused-finalize apply) ----
template <int C>
__global__ __launch_bounds__(256) void bn_stats_bf16_k(
    const unsigned short* __restrict__ x, const int* __restrict__ ndev, int nhost,
    float* __restrict__ sums) {
  constexpr int RPB = 256 / C;
  const int n = (nhost >= 0) ? nhost : __ldg(ndev);
  const int c = threadIdx.x % C;
  const int rsub = threadIdx.x / C;
  float s = 0.f, ss = 0.f;
  const long step = (long)gridDim.x * RPB;
  for (long r = (long)blockIdx.x * RPB + rsub; r < n; r += step) {
    const float v = bf2f(x[r * C + c]);
    s += v;
    ss = fmaf(v, v, ss);
  }
  __shared__ float sh[2][256];
  sh[0][threadIdx.x] = s;
  sh[1][threadIdx.x] = ss;
  __syncthreads();
  if (rsub == 0) {
#pragma unroll
    for (int j = 1; j < RPB; ++j) { s += sh[0][c + j * C]; ss += sh[1][c + j * C]; }
    atomicAdd(&sums[c], s);
    atomicAdd(&sums[C + c], ss);
  }
}

__global__ void bn_apply_bf16_k(unsigned short* __restrict__ x, int c8,
                                const float* __restrict__ sums,
                                const float* __restrict__ g, const float* __restrict__ b,
                                int C, const int* __restrict__ ndev, int nhost) {
  const int n = (nhost >= 0) ? nhost : __ldg(ndev);
  __shared__ float sb[512];
  const float fn = (float)n;
  for (int c = threadIdx.x; c < C; c += blockDim.x) {
    const float mean = sums[c] / fn;
    const float var = sums[C + c] / fn - mean * mean;
    const float sc = g[c] * rsqrtf(var + 1e-5f);
    sb[c] = sc;
    sb[C + c] = fmaf(-mean, sc, b[c]);
  }
  __syncthreads();
  const long total = (long)n * c8;
  const long stride = (long)gridDim.x * blockDim.x;
  for (long i = (long)blockIdx.x * blockDim.x + threadIdx.x; i < total; i += stride) {
    const int c0 = (int)(i & (c8 - 1)) << 3;
    uint4 v = *reinterpret_cast<uint4*>(x + i * 8);
    unsigned int uu[4] = {v.x, v.y, v.z, v.w};
#pragma unroll
    for (int q = 0; q < 4; ++q) {
      const float v0 = bf2f((unsigned short)(uu[q] & 0xffffu));
      const float v1 = bf2f((unsigned short)(uu[q] >> 16));
      const int cA = c0 + 2 * q, cB = c0 + 2 * q + 1;
      const float r0 = fmaxf(fmaf(v0, sb[cA], sb[C + cA]), 0.f);
      const float r1 = fmaxf(fmaf(v1, sb[cB], sb[C + cB]), 0.f);
      uu[q] = (unsigned int)f2bf(r0) | ((unsigned int)f2bf(r1) << 16);
    }
    v.x = uu[0]; v.y = uu[1]; v.z = uu[2]; v.w = uu[3];
    *reinterpret_cast<uint4*>(x + i * 8) = v;
  }
}

// out[N0,20] = concat(BNReLU(t2raw), e1bn) @ Wf ; t2's BN folded
__global__ __launch_bounds__(256) void final_gemm_k(
    const unsigned short* __restrict__ t2raw, const unsigned short* __restrict__ e1,
    const float* __restrict__ Wf, const float* __restrict__ sums,
    const float* __restrict__ g, const float* __restrict__ b,
    float* __restrict__ out, int n0) {
  __shared__ float w[64 * 20];
  __shared__ float sb[64];
  for (int i = threadIdx.x; i < 64 * 20; i += 256) w[i] = Wf[i];
  if (threadIdx.x < 32) {
    const int c = threadIdx.x;
    const float fn = (float)n0;
    const float mean = sums[c] / fn;
    const float var = sums[32 + c] / fn - mean * mean;
    const float sc = g[c] * rsqrtf(var + 1e-5f);
    sb[c] = sc;
    sb[32 + c] = fmaf(-mean, sc, b[c]);
  }
  __syncthreads();
  const int r = blockIdx.x * 256 + threadIdx.x;
  if (r >= n0) return;
  float acc[20];
#pragma unroll
  for (int c = 0; c < 20; ++c) acc[c] = 0.f;
  const unsigned short* __restrict__ rowA = t2raw + (size_t)r * 32;
  const unsigned short* __restrict__ rowB = e1 + (size_t)r * 32;
#pragma unroll
  for (int j = 0; j < 32; ++j) {
    const float av = fmaxf(fmaf(bf2f(rowA[j]), sb[j], sb[32 + j]), 0.f);
#pragma unroll
    for (int c = 0; c < 20; ++c) acc[c] = fmaf(av, w[j * 20 + c], acc[c]);
  }
#pragma unroll
  for (int j = 0; j < 32; ++j) {
    const float av = bf2f(rowB[j]);
#pragma unroll
    for (int c = 0; c < 20; ++c) acc[c] = fmaf(av, w[(32 + j) * 20 + c], acc[c]);
  }
  float* __restrict__ orow = out + (size_t)r * 20;
#pragma unroll
  for (int c = 0; c < 20; ++c) orow[c] = acc[c];
}

// ---------------------------------------------------------------------------

extern "C" void kernel_launch(void* const* d_in, const int* in_sizes, int n_in,
                              void* d_out, int out_size, void* d_ws, size_t ws_size,
                              hipStream_t stream) {
  const float* feats = (const float*)d_in[0];
  const float* W1 = (const float*)d_in[1];
  const float* W2 = (const float*)d_in[2];
  const float* W3 = (const float*)d_in[3];
  const float* W4 = (const float*)d_in[4];
  const float* D4w = (const float*)d_in[5];
  const float* D3w = (const float*)d_in[6];
  const float* D2w = (const float*)d_in[7];
  const float* Wf = (const float*)d_in[8];
  const float* g1 = (const float*)d_in[9];   const float* b1 = (const float*)d_in[10];
  const float* g2 = (const float*)d_in[11];  const float* b2 = (const float*)d_in[12];
  const float* g3 = (const float*)d_in[13];  const float* b3 = (const float*)d_in[14];
  const float* g4 = (const float*)d_in[15];  const float* b4 = (const float*)d_in[16];
  const float* gd4 = (const float*)d_in[17]; const float* bd4 = (const float*)d_in[18];
  const float* gd3 = (const float*)d_in[19]; const float* bd3 = (const float*)d_in[20];
  const float* gd2 = (const float*)d_in[21]; const float* bd2 = (const float*)d_in[22];
  const int* m1i = (const int*)d_in[23]; const int* m1o = (const int*)d_in[24];
  const int* m2i = (const int*)d_in[25]; const int* m2o = (const int*)d_in[26];
  const int* m3i = (const int*)d_in[27]; const int* m3o = (const int*)d_in[28];
  const int* m4i = (const int*)d_in[29]; const int* m4o = (const int*)d_in[30];
  const int* n1d = (const int*)d_in[31];
  const int* n2d = (const int*)d_in[32];
  const int* n3d = (const int*)d_in[33];

  const int N0 = in_sizes[0] / 4;
  const int P1 = in_sizes[23] / 27;
  const int P2 = in_sizes[25] / 27;
  const int P3 = in_sizes[27] / 27;
  const int P4 = in_sizes[29] / 27;
  const int MAXN2 = (N0 < 65536) ? N0 : 65536;  // 2 * 32^3
  const int MAXN3 = (N0 < 8192) ? N0 : 8192;    // 2 * 16^3

  char* wsb = (char*)d_ws;
  size_t off = 0;
  auto alloc = [&](size_t bytes) {
    char* p = wsb + off;
    off = (off + bytes + 255) & ~(size_t)255;
    return p;
  };
  float* stats = (float*)alloc(7 * 1024 * 4);
  int* base7 = (int*)alloc(6 * 32 * 4);
  int* invT = (int*)alloc((size_t)28 * N0 * 4);
  unsigned short* e1 = (unsigned short*)alloc((size_t)N0 * 32 * 2);
  unsigned short* e2 = (unsigned short*)alloc((size_t)N0 * 64 * 2);
  unsigned short* e3 = (unsigned short*)alloc((size_t)MAXN2 * 128 * 2);
  unsigned short* e4 = (unsigned short*)alloc((size_t)MAXN3 * 256 * 2);
  unsigned short* t4 = (unsigned short*)alloc((size_t)MAXN2 * 128 * 2);
  unsigned short* t3 = (unsigned short*)alloc((size_t)N0 * 64 * 2);
  unsigned short* t2 = (unsigned short*)alloc((size_t)N0 * 32 * 2);
  unsigned short* Wf2 = (unsigned short*)alloc((size_t)27 * 32 * 64 * 2);
  unsigned short* Wf3 = (unsigned short*)alloc((size_t)27 * 64 * 128 * 2);
  unsigned short* Wf4 = (unsigned short*)alloc((size_t)27 * 128 * 256 * 2);
  unsigned short* WfD4 = (unsigned short*)alloc((size_t)27 * 256 * 128 * 2);
  unsigned short* WfD3 = (unsigned short*)alloc((size_t)27 * 256 * 64 * 2);
  unsigned short* WfD2 = (unsigned short*)alloc((size_t)27 * 128 * 32 * 2);
  size_t cmax = (size_t)27 * P2 * 64;
  { size_t v;
    v = (size_t)27 * P3 * 128; if (v > cmax) cmax = v;
    v = (size_t)27 * P4 * 128; if (v > cmax) cmax = v;
    v = (size_t)27 * P3 * 64;  if (v > cmax) cmax = v;
    v = (size_t)27 * P2 * 32;  if (v > cmax) cmax = v; }
  unsigned short* contrib = (unsigned short*)alloc(cmax * 2);
  if (off > ws_size) return;  // loud fail if scratch too small

  hipMemsetAsync(stats, 0, 7 * 1024 * 4, stream);
  const dim3 blk(256);
#define ST(i) (stats + (i)*1024)
#define FGRID(n) dim3((unsigned)CDIV((long)(n) * 28, 256))

  // ---- batched weight prep ----
  {
    PrepArgs pa;
    pa.src[0] = W2;  pa.dst[0] = Wf2;  pa.cin[0] = 32;  pa.cout[0] = 64;
    pa.src[1] = W3;  pa.dst[1] = Wf3;  pa.cin[1] = 64;  pa.cout[1] = 128;
    pa.src[2] = W4;  pa.dst[2] = Wf4;  pa.cin[2] = 128; pa.cout[2] = 256;
    pa.src[3] = D4w; pa.dst[3] = WfD4; pa.cin[3] = 256; pa.cout[3] = 128;
    pa.src[4] = D3w; pa.dst[4] = WfD3; pa.cin[4] = 256; pa.cout[4] = 64;
    pa.src[5] = D2w; pa.dst[5] = WfD2; pa.cin[5] = 128; pa.cout[5] = 32;
    int acc = 0;
    for (int i = 0; i < 6; ++i) {
      pa.cstart[i] = acc;
      acc += 27 * (pa.cin[i] / 32) * (pa.cout[i] / 16);
    }
    pa.cstart[6] = acc;
    prep_all_k<<<CDIV(acc, 4), blk, 0, stream>>>(pa);
  }
  kmap_all_k<<<6, 32, 0, stream>>>(m2o, P2, n1d, m3o, P3, n2d, m4o, P4, n3d,
                                   m4i, m3i, m2i, N0, base7);

  // ---- conv1: 4->32 thread-per-row ----
  fillT_k<<<FGRID(N0), blk, 0, stream>>>(invT, nullptr, N0);
  inv_build_k<<<dim3(CDIV(P1, 256), 27), blk, 0, stream>>>(m1i, m1o, P1, N0, invT);
  conv1_k<<<CDIV(N0, 256), blk, 0, stream>>>(feats, W1, invT, N0, e1);
  bn_stats_bf16_k<32><<<512, blk, 0, stream>>>(e1, nullptr, N0, ST(0));
  bn_apply_bf16_k<<<1024, blk, 0, stream>>>(e1, 4, ST(0), g1, b1, 32, nullptr, N0);

  // ---- conv2: 32->64 compact, ARM=4 ----
  fillT_k<<<FGRID(N0), blk, 0, stream>>>(invT, n1d, -1);
  inv_scatter_k<<<dim3(CDIV(P2, 256), 27), blk, 0, stream>>>(m2o, P2, base7 + 0 * 32, invT);
  pgemm_k<32, 0, 64, 1, 4><<<dim3(CDIV(P2, 256), 27), blk, 0, stream>>>(
      e1, nullptr, Wf2, m2i, P2, base7 + 0 * 32, contrib, 0, 64);
  reduce_bf16_k<64><<<CDIV(N0, 32), blk, 0, stream>>>(contrib, invT, n1d, -1, e2, 64, 0);
  bn_stats_bf16_k<64><<<512, blk, 0, stream>>>(e2, n1d, -1, ST(1));
  bn_apply_bf16_k<<<1024, blk, 0, stream>>>(e2, 8, ST(1), g2, b2, 64, n1d, -1);

  // ---- conv3: 64->128 compact ----
  fillT_k<<<FGRID(MAXN2), blk, 0, stream>>>(invT, n2d, -1);
  inv_scatter_k<<<dim3(CDIV(P3, 256), 27), blk, 0, stream>>>(m3o, P3, base7 + 1 * 32, invT);
  pgemm_k<64, 0, 128, 1, 2><<<dim3(CDIV(P3, 128), 27), blk, 0, stream>>>(
      e2, nullptr, Wf3, m3i, P3, base7 + 1 * 32, contrib, 0, 128);
  reduce_bf16_k<128><<<CDIV(MAXN2, 16), blk, 0, stream>>>(contrib, invT, n2d, -1, e3, 128, 0);
  bn_stats_bf16_k<128><<<512, blk, 0, stream>>>(e3, n2d, -1, ST(2));
  bn_apply_bf16_k<<<1024, blk, 0, stream>>>(e3, 16, ST(2), g3, b3, 128, n2d, -1);

  // ---- conv4: 128->256 compact, two column halves ----
  fillT_k<<<FGRID(MAXN3), blk, 0, stream>>>(invT, n3d, -1);
  inv_scatter_k<<<dim3(CDIV(P4, 256), 27), blk, 0, stream>>>(m4o, P4, base7 + 2 * 32, invT);
  for (int cb = 0; cb < 2; ++cb) {
    pgemm_k<128, 0, 256, 2, 2><<<dim3(CDIV(P4, 128), 27), blk, 0, stream>>>(
        e3, nullptr, Wf4, m4i, P4, base7 + 2 * 32, contrib, cb, 128);
    reduce_bf16_k<128><<<CDIV(MAXN3, 16), blk, 0, stream>>>(
        contrib, invT, n3d, -1, e4, 256, cb * 128);
  }
  bn_stats_bf16_k<256><<<512, blk, 0, stream>>>(e4, n3d, -1, ST(3));
  bn_apply_bf16_k<<<512, blk, 0, stream>>>(e4, 32, ST(3), g4, b4, 256, n3d, -1);

  // ---- D4: tconv 256->128 compact (maps swapped), unsplit ----
  fillT_k<<<FGRID(MAXN2), blk, 0, stream>>>(invT, n2d, -1);
  inv_scatter_k<<<dim3(CDIV(P4, 256), 27), blk, 0, stream>>>(m4i, P4, base7 + 3 * 32, invT);
  pgemm_k<256, 0, 128, 1, 2><<<dim3(CDIV(P4, 128), 27), blk, 0, stream>>>(
      e4, nullptr, WfD4, m4o, P4, base7 + 3 * 32, contrib, 0, 128);
  reduce_bf16_k<128><<<CDIV(MAXN2, 16), blk, 0, stream>>>(contrib, invT, n2d, -1, t4, 128, 0);
  bn_stats_bf16_k<128><<<512, blk, 0, stream>>>(t4, n2d, -1, ST(4));
  bn_apply_bf16_k<<<1024, blk, 0, stream>>>(t4, 16, ST(4), gd4, bd4, 128, n2d, -1);

  // ---- D3: tconv concat(t4,e3)=256 -> 64 compact ----
  fillT_k<<<FGRID(N0), blk, 0, stream>>>(invT, n1d, -1);
  inv_scatter_k<<<dim3(CDIV(P3, 256), 27), blk, 0, stream>>>(m3i, P3, base7 + 4 * 32, invT);
  pgemm_k<128, 128, 64, 1, 2><<<dim3(CDIV(P3, 128), 27), blk, 0, stream>>>(
      t4, e3, WfD3, m3o, P3, base7 + 4 * 32, contrib, 0, 64);
  reduce_bf16_k<64><<<CDIV(N0, 32), blk, 0, stream>>>(contrib, invT, n1d, -1, t3, 64, 0);
  bn_stats_bf16_k<64><<<512, blk, 0, stream>>>(t3, n1d, -1, ST(5));
  bn_apply_bf16_k<<<1024, blk, 0, stream>>>(t3, 8, ST(5), gd3, bd3, 64, n1d, -1);

  // ---- D2: tconv concat(t3,e2)=128 -> 32 compact (t2 BN folded into final) ----
  fillT_k<<<FGRID(N0), blk, 0, stream>>>(invT, nullptr, N0);
  inv_scatter_k<<<dim3(CDIV(P2, 256), 27), blk, 0, stream>>>(m2i, P2, base7 + 5 * 32, invT);
  pgemm_k<64, 64, 32, 1, 2><<<dim3(CDIV(P2, 128), 27), blk, 0, stream>>>(
      t3, e2, WfD2, m2o, P2, base7 + 5 * 32, contrib, 0, 32);
  reduce_bf16_k<32><<<CDIV(N0, 64), blk, 0, stream>>>(contrib, invT, nullptr, N0, t2, 32, 0);
  bn_stats_bf16_k<32><<<512, blk, 0, stream>>>(t2, nullptr, N0, ST(6));

  // ---- final 1x1 with fused t2 BN+ReLU ----
  final_gemm_k<<<CDIV(N0, 256), blk, 0, stream>>>(
      t2, e1, Wf, ST(6), gd2, bd2, (float*)d_out, N0);

#undef ST
#undef FGRID
}

// Round 15
// 609.226 us; speedup vs baseline: 1.0251x; 1.0251x over previous
//
#include <hip/hip_runtime.h>

// ---------------------------------------------------------------------------
// Sparse 3D U-Net, round 15: r14 + conv1 4-way column split (64 rows x 4
// col-threads per block, grid 4x, per-thread work 4x smaller).
// ---------------------------------------------------------------------------

#define CDIV(a, b) (((a) + (b)-1) / (b))

typedef __attribute__((ext_vector_type(8))) short bf16x8;
typedef __attribute__((ext_vector_type(4))) float f32x4;

__device__ __forceinline__ unsigned short f2bf(float f) {
  union { float f; unsigned int u; } x{f};
  const unsigned int r = x.u + 0x7fffu + ((x.u >> 16) & 1u);
  return (unsigned short)(r >> 16);
}
__device__ __forceinline__ float bf2f(unsigned short h) {
  union { unsigned int u; float f; } x{(unsigned int)h << 16};
  return x.f;
}
__device__ __forceinline__ unsigned int pk2(float a, float b) {
  return (unsigned int)f2bf(a) | ((unsigned int)f2bf(b) << 16);
}

// linear fill of inv_T rows [0,n): 28n ints = -1
__global__ void fillT_k(int* __restrict__ invT, const int* __restrict__ ndev, int nhost) {
  const int n = (nhost >= 0) ? nhost : __ldg(ndev);
  const long total = (long)n * 28;
  const long i = (long)blockIdx.x * 256 + threadIdx.x;
  if (i < total) invT[i] = -1;
}

// all 6 pgemm-layer kmaps in one launch; base7[L*32 + 0..27]
__global__ void kmap_all_k(const int* __restrict__ m2o, int P2, const int* __restrict__ n1d,
                           const int* __restrict__ m3o, int P3, const int* __restrict__ n2d,
                           const int* __restrict__ m4o, int P4, const int* __restrict__ n3d,
                           const int* __restrict__ m4i, const int* __restrict__ m3i,
                           const int* __restrict__ m2i, int N0, int* __restrict__ base7) {
  const int L = blockIdx.x;
  const int* om; int P, n;
  switch (L) {
    case 0: om = m2o; P = P2; n = __ldg(n1d); break;
    case 1: om = m3o; P = P3; n = __ldg(n2d); break;
    case 2: om = m4o; P = P4; n = __ldg(n3d); break;
    case 3: om = m4i; P = P4; n = __ldg(n2d); break;
    case 4: om = m3i; P = P3; n = __ldg(n1d); break;
    default: om = m2i; P = P2; n = N0; break;
  }
  __shared__ int cnt[27];
  const int k = threadIdx.x;
  if (k < 27) {
    const int* __restrict__ row = om + (long)k * P;
    int lo = 0, hi = P;
    while (lo < hi) {
      const int mid = (lo + hi) >> 1;
      if (row[mid] < n) lo = mid + 1; else hi = mid;
    }
    cnt[k] = lo;
  }
  __syncthreads();
  if (threadIdx.x == 0) {
    int acc = 0;
    int* b = base7 + L * 32;
    for (int j = 0; j < 27; ++j) { b[j] = acc; acc += cnt[j]; }
    b[27] = acc;
  }
}

// inv_T[om[k][p]*28 + k] = base[k] + p
__global__ void inv_scatter_k(const int* __restrict__ om, int P,
                              const int* __restrict__ base,
                              int* __restrict__ invT) {
  const int k = blockIdx.y;
  const int b0 = base[k];
  const int cnt = base[k + 1] - b0;
  const int p0 = blockIdx.x * 256;
  if (p0 >= cnt) return;
  const int p = p0 + threadIdx.x;
  if (p < cnt) invT[(size_t)om[(long)k * P + p] * 28 + k] = b0 + p;
}

// inv_T[om[k][p]*28 + k] = im[k][p] for valid pairs (conv1 path)
__global__ void inv_build_k(const int* __restrict__ im, const int* __restrict__ om,
                            int P, int n, int* __restrict__ invT) {
  const int k = blockIdx.y;
  const int p = blockIdx.x * 256 + threadIdx.x;
  if (p >= P) return;
  const int o = om[(long)k * P + p];
  if (o < n) invT[(size_t)o * 28 + k] = im[(long)k * P + p];
}

// batched weight prep: all 6 W tensors -> frag-ordered bf16, one launch
struct PrepArgs {
  const float* src[6];
  unsigned short* dst[6];
  int cin[6], cout[6], cstart[7];
};
__global__ __launch_bounds__(256) void prep_all_k(PrepArgs pa) {
  const int c = blockIdx.x * 4 + (threadIdx.x >> 6);
  if (c >= pa.cstart[6]) return;
  int ws = 0;
  while (c >= pa.cstart[ws + 1]) ++ws;
  const int local = c - pa.cstart[ws];
  const int CIN = pa.cin[ws], COUT = pa.cout[ws];
  const int NCC = COUT >> 4, NKK = CIN >> 5;
  const int cc = local % NCC;
  const int kk = (local / NCC) % NKK;
  const int k = local / (NCC * NKK);
  const int l = threadIdx.x & 63;
  const float* __restrict__ src =
      pa.src[ws] + ((size_t)k * CIN + kk * 32 + (l >> 4) * 8) * COUT + cc * 16 + (l & 15);
  unsigned short* __restrict__ dst = pa.dst[ws] + (size_t)local * 512 + l * 8;
#pragma unroll
  for (int j = 0; j < 8; ++j) dst[j] = f2bf(src[(size_t)j * COUT]);
}

// Phase 1: compact per-offset pair GEMM (optional column split via cb).
template <int CIN1, int CIN2, int COUT, int NCB, int ARM>
__global__ __launch_bounds__(256) void pgemm_k(
    const unsigned short* __restrict__ actA, const unsigned short* __restrict__ actB,
    const unsigned short* __restrict__ Wf, const int* __restrict__ im, int P,
    const int* __restrict__ base, unsigned short* __restrict__ contrib,
    int cb, int cstride) {
  constexpr int CIN = CIN1 + CIN2;
  constexpr int NKK = CIN / 32;
  constexpr int NCCt = COUT / 16;
  constexpr int NCCb = NCCt / NCB;
  constexpr int T = NKK * NCCb;
  constexpr int SPAN = 4 * ARM * 16;
  __shared__ unsigned short wl[T * 512];

  const int k = blockIdx.y;
  const int b0 = base[k];
  const int cnt = base[k + 1] - b0;
  if ((int)blockIdx.x * SPAN >= cnt) return;

  const int w = threadIdx.x >> 6;
  const int l = threadIdx.x & 63;
  for (int t = w; t < T; t += 4) {
    const int kk_ = t / NCCb, ccl_ = t - kk_ * NCCb;
    const unsigned short* src =
        Wf + (((size_t)k * NKK + kk_) * NCCt + cb * NCCb + ccl_) * 512 + l * 8;
    __builtin_amdgcn_global_load_lds(
        (const __attribute__((address_space(1))) unsigned int*)src,
        (__attribute__((address_space(3))) unsigned int*)(wl + t * 512), 16, 0, 0);
  }
  __syncthreads();  // W staged

  const int lrow = l & 15, lgrp = l >> 4;
  const int t0 = blockIdx.x * SPAN + w * (ARM * 16);

  bf16x8 a[ARM][NKK];
#pragma unroll
  for (int rm = 0; rm < ARM; ++rm) {
    const int p = t0 + rm * 16 + lrow;
    const int iv = (p < cnt) ? im[(size_t)k * P + p] : -1;
#pragma unroll
    for (int kk = 0; kk < NKK; ++kk) {
      if (iv >= 0) {
        const int cbs = kk * 32 + lgrp * 8;
        a[rm][kk] = (CIN2 == 0 || cbs < CIN1)
            ? *reinterpret_cast<const bf16x8*>(actA + (size_t)iv * CIN1 + cbs)
            : *reinterpret_cast<const bf16x8*>(actB + (size_t)iv * CIN2 + (cbs - CIN1));
      } else {
        a[rm][kk] = (bf16x8){0, 0, 0, 0, 0, 0, 0, 0};
      }
    }
  }

  f32x4 acc[ARM][NCCb];
#pragma unroll
  for (int rm = 0; rm < ARM; ++rm)
#pragma unroll
    for (int cc = 0; cc < NCCb; ++cc) acc[rm][cc] = (f32x4){0.f, 0.f, 0.f, 0.f};

#pragma unroll
  for (int kk = 0; kk < NKK; ++kk)
#pragma unroll
    for (int cc = 0; cc < NCCb; ++cc) {
      const bf16x8 b =
          *reinterpret_cast<const bf16x8*>(wl + ((kk * NCCb + cc) * 64 + l) * 8);
#pragma unroll
      for (int rm = 0; rm < ARM; ++rm)
        acc[rm][cc] = __builtin_amdgcn_mfma_f32_16x16x32_bf16(a[rm][kk], b, acc[rm][cc], 0, 0, 0);
    }

#pragma unroll
  for (int rm = 0; rm < ARM; ++rm)
#pragma unroll
    for (int cc = 0; cc < NCCb; ++cc)
#pragma unroll
      for (int r = 0; r < 4; ++r) {
        const int p = t0 + rm * 16 + lgrp * 4 + r;
        if (p < cnt)
          contrib[(size_t)(b0 + p) * cstride + cc * 16 + lrow] = f2bf(acc[rm][cc][r]);
      }
}

// Phase 2: out[o, coff:+COLS] = sum_k contrib[inv_T[o][k]]
template <int COLS>
__global__ __launch_bounds__(256) void reduce_bf16_k(
    const unsigned short* __restrict__ contrib, const int* __restrict__ invT,
    const int* __restrict__ ndev, int nhost, unsigned short* __restrict__ out,
    int ldo, int coff) {
  constexpr int TPR = COLS / 8;
  constexpr int RPB = 256 / TPR;
  const int n = (nhost >= 0) ? nhost : __ldg(ndev);
  const int r0 = blockIdx.x * RPB;
  if (r0 >= n) return;
  __shared__ int iv[RPB][28];
  for (int i = threadIdx.x; i < RPB * 28; i += 256) {
    const int r = i / 28, k = i - r * 28;
    iv[r][k] = (r0 + r < n && k < 27) ? invT[(size_t)(r0 + r) * 28 + k] : -1;
  }
  __syncthreads();
  const int r = threadIdx.x / TPR;
  const int c8 = (threadIdx.x % TPR) * 8;
  if (r0 + r >= n) return;
  float s[8] = {0.f, 0.f, 0.f, 0.f, 0.f, 0.f, 0.f, 0.f};
#pragma unroll
  for (int k = 0; k < 27; ++k) {
    const int p = iv[r][k];
    if (p >= 0) {
      const bf16x8 v = *reinterpret_cast<const bf16x8*>(contrib + (size_t)p * COLS + c8);
#pragma unroll
      for (int j = 0; j < 8; ++j) s[j] += bf2f((unsigned short)v[j]);
    }
  }
  bf16x8 o;
#pragma unroll
  for (int j = 0; j < 8; ++j) o[j] = (short)f2bf(s[j]);
  *reinterpret_cast<bf16x8*>(out + (size_t)(r0 + r) * ldo + coff + c8) = o;
}

// conv1: 4 threads per row (8 cols each); grid 4x for occupancy.
__global__ __launch_bounds__(256) void conv1_k(
    const float* __restrict__ feats, const float* __restrict__ W1,
    const int* __restrict__ invT, int n0, unsigned short* __restrict__ e1) {
  __shared__ float w[27 * 128];
  for (int i = threadIdx.x; i < 27 * 128; i += 256) w[i] = W1[i];
  __syncthreads();
  const int t = blockIdx.x * 256 + threadIdx.x;
  const int r = t >> 2;
  const int tq = t & 3;  // col quarter: float4 cols tq*2, tq*2+1
  if (r >= n0) return;
  int ivk[28];
  const int4* __restrict__ ivsrc = reinterpret_cast<const int4*>(invT + (size_t)r * 28);
#pragma unroll
  for (int j = 0; j < 7; ++j) {
    const int4 v = ivsrc[j];  // same addr across 4 lanes -> broadcast
    ivk[j * 4 + 0] = v.x; ivk[j * 4 + 1] = v.y; ivk[j * 4 + 2] = v.z; ivk[j * 4 + 3] = v.w;
  }
  float4 acc0 = make_float4(0.f, 0.f, 0.f, 0.f);
  float4 acc1 = make_float4(0.f, 0.f, 0.f, 0.f);
  const int qq = tq * 2;
#pragma unroll
  for (int k = 0; k < 27; ++k) {
    const int iv = ivk[k];
    if (iv < 0) continue;
    const float4 f = *reinterpret_cast<const float4*>(feats + (size_t)iv * 4);
    const float4* __restrict__ wr = reinterpret_cast<const float4*>(&w[k * 128]);
    {
      const float4 w0 = wr[qq], w1 = wr[8 + qq], w2 = wr[16 + qq], w3 = wr[24 + qq];
      acc0.x += f.x * w0.x + f.y * w1.x + f.z * w2.x + f.w * w3.x;
      acc0.y += f.x * w0.y + f.y * w1.y + f.z * w2.y + f.w * w3.y;
      acc0.z += f.x * w0.z + f.y * w1.z + f.z * w2.z + f.w * w3.z;
      acc0.w += f.x * w0.w + f.y * w1.w + f.z * w2.w + f.w * w3.w;
    }
    {
      const float4 w0 = wr[qq + 1], w1 = wr[9 + qq], w2 = wr[17 + qq], w3 = wr[25 + qq];
      acc1.x += f.x * w0.x + f.y * w1.x + f.z * w2.x + f.w * w3.x;
      acc1.y += f.x * w0.y + f.y * w1.y + f.z * w2.y + f.w * w3.y;
      acc1.z += f.x * w0.z + f.y * w1.z + f.z * w2.z + f.w * w3.z;
      acc1.w += f.x * w0.w + f.y * w1.w + f.z * w2.w + f.w * w3.w;
    }
  }
  const uint4 o = make_uint4(pk2(acc0.x, acc0.y), pk2(acc0.z, acc0.w),
                             pk2(acc1.x, acc1.y), pk2(acc1.z, acc1.w));
  *reinterpret_cast<uint4*>(e1 + (size_t)r * 32 + tq * 8) = o;
}

// ---- BN (grid-stride stats + fused-finalize apply) ----
template <int C>
__global__ __launch_bounds__(256) void bn_stats_bf16_k(
    const unsigned short* __restrict__ x, const int* __restrict__ ndev, int nhost,
    float* __restrict__ sums) {
  constexpr int RPB = 256 / C;
  const int n = (nhost >= 0) ? nhost : __ldg(ndev);
  const int c = threadIdx.x % C;
  const int rsub = threadIdx.x / C;
  float s = 0.f, ss = 0.f;
  const long step = (long)gridDim.x * RPB;
  for (long r = (long)blockIdx.x * RPB + rsub; r < n; r += step) {
    const float v = bf2f(x[r * C + c]);
    s += v;
    ss = fmaf(v, v, ss);
  }
  __shared__ float sh[2][256];
  sh[0][threadIdx.x] = s;
  sh[1][threadIdx.x] = ss;
  __syncthreads();
  if (rsub == 0) {
#pragma unroll
    for (int j = 1; j < RPB; ++j) { s += sh[0][c + j * C]; ss += sh[1][c + j * C]; }
    atomicAdd(&sums[c], s);
    atomicAdd(&sums[C + c], ss);
  }
}

__global__ void bn_apply_bf16_k(unsigned short* __restrict__ x, int c8,
                                const float* __restrict__ sums,
                                const float* __restrict__ g, const float* __restrict__ b,
                                int C, const int* __restrict__ ndev, int nhost) {
  const int n = (nhost >= 0) ? nhost : __ldg(ndev);
  __shared__ float sb[512];
  const float fn = (float)n;
  for (int c = threadIdx.x; c < C; c += blockDim.x) {
    const float mean = sums[c] / fn;
    const float var = sums[C + c] / fn - mean * mean;
    const float sc = g[c] * rsqrtf(var + 1e-5f);
    sb[c] = sc;
    sb[C + c] = fmaf(-mean, sc, b[c]);
  }
  __syncthreads();
  const long total = (long)n * c8;
  const long stride = (long)gridDim.x * blockDim.x;
  for (long i = (long)blockIdx.x * blockDim.x + threadIdx.x; i < total; i += stride) {
    const int c0 = (int)(i & (c8 - 1)) << 3;
    uint4 v = *reinterpret_cast<uint4*>(x + i * 8);
    unsigned int uu[4] = {v.x, v.y, v.z, v.w};
#pragma unroll
    for (int q = 0; q < 4; ++q) {
      const float v0 = bf2f((unsigned short)(uu[q] & 0xffffu));
      const float v1 = bf2f((unsigned short)(uu[q] >> 16));
      const int cA = c0 + 2 * q, cB = c0 + 2 * q + 1;
      const float r0 = fmaxf(fmaf(v0, sb[cA], sb[C + cA]), 0.f);
      const float r1 = fmaxf(fmaf(v1, sb[cB], sb[C + cB]), 0.f);
      uu[q] = (unsigned int)f2bf(r0) | ((unsigned int)f2bf(r1) << 16);
    }
    v.x = uu[0]; v.y = uu[1]; v.z = uu[2]; v.w = uu[3];
    *reinterpret_cast<uint4*>(x + i * 8) = v;
  }
}

// out[N0,20] = concat(BNReLU(t2raw), e1bn) @ Wf ; t2's BN folded
__global__ __launch_bounds__(256) void final_gemm_k(
    const unsigned short* __restrict__ t2raw, const unsigned short* __restrict__ e1,
    const float* __restrict__ Wf, const float* __restrict__ sums,
    const float* __restrict__ g, const float* __restrict__ b,
    float* __restrict__ out, int n0) {
  __shared__ float w[64 * 20];
  __shared__ float sb[64];
  for (int i = threadIdx.x; i < 64 * 20; i += 256) w[i] = Wf[i];
  if (threadIdx.x < 32) {
    const int c = threadIdx.x;
    const float fn = (float)n0;
    const float mean = sums[c] / fn;
    const float var = sums[32 + c] / fn - mean * mean;
    const float sc = g[c] * rsqrtf(var + 1e-5f);
    sb[c] = sc;
    sb[32 + c] = fmaf(-mean, sc, b[c]);
  }
  __syncthreads();
  const int r = blockIdx.x * 256 + threadIdx.x;
  if (r >= n0) return;
  float acc[20];
#pragma unroll
  for (int c = 0; c < 20; ++c) acc[c] = 0.f;
  const unsigned short* __restrict__ rowA = t2raw + (size_t)r * 32;
  const unsigned short* __restrict__ rowB = e1 + (size_t)r * 32;
#pragma unroll
  for (int j = 0; j < 32; ++j) {
    const float av = fmaxf(fmaf(bf2f(rowA[j]), sb[j], sb[32 + j]), 0.f);
#pragma unroll
    for (int c = 0; c < 20; ++c) acc[c] = fmaf(av, w[j * 20 + c], acc[c]);
  }
#pragma unroll
  for (int j = 0; j < 32; ++j) {
    const float av = bf2f(rowB[j]);
#pragma unroll
    for (int c = 0; c < 20; ++c) acc[c] = fmaf(av, w[(32 + j) * 20 + c], acc[c]);
  }
  float* __restrict__ orow = out + (size_t)r * 20;
#pragma unroll
  for (int c = 0; c < 20; ++c) orow[c] = acc[c];
}

// ---------------------------------------------------------------------------

extern "C" void kernel_launch(void* const* d_in, const int* in_sizes, int n_in,
                              void* d_out, int out_size, void* d_ws, size_t ws_size,
                              hipStream_t stream) {
  const float* feats = (const float*)d_in[0];
  const float* W1 = (const float*)d_in[1];
  const float* W2 = (const float*)d_in[2];
  const float* W3 = (const float*)d_in[3];
  const float* W4 = (const float*)d_in[4];
  const float* D4w = (const float*)d_in[5];
  const float* D3w = (const float*)d_in[6];
  const float* D2w = (const float*)d_in[7];
  const float* Wf = (const float*)d_in[8];
  const float* g1 = (const float*)d_in[9];   const float* b1 = (const float*)d_in[10];
  const float* g2 = (const float*)d_in[11];  const float* b2 = (const float*)d_in[12];
  const float* g3 = (const float*)d_in[13];  const float* b3 = (const float*)d_in[14];
  const float* g4 = (const float*)d_in[15];  const float* b4 = (const float*)d_in[16];
  const float* gd4 = (const float*)d_in[17]; const float* bd4 = (const float*)d_in[18];
  const float* gd3 = (const float*)d_in[19]; const float* bd3 = (const float*)d_in[20];
  const float* gd2 = (const float*)d_in[21]; const float* bd2 = (const float*)d_in[22];
  const int* m1i = (const int*)d_in[23]; const int* m1o = (const int*)d_in[24];
  const int* m2i = (const int*)d_in[25]; const int* m2o = (const int*)d_in[26];
  const int* m3i = (const int*)d_in[27]; const int* m3o = (const int*)d_in[28];
  const int* m4i = (const int*)d_in[29]; const int* m4o = (const int*)d_in[30];
  const int* n1d = (const int*)d_in[31];
  const int* n2d = (const int*)d_in[32];
  const int* n3d = (const int*)d_in[33];

  const int N0 = in_sizes[0] / 4;
  const int P1 = in_sizes[23] / 27;
  const int P2 = in_sizes[25] / 27;
  const int P3 = in_sizes[27] / 27;
  const int P4 = in_sizes[29] / 27;
  const int MAXN2 = (N0 < 65536) ? N0 : 65536;  // 2 * 32^3
  const int MAXN3 = (N0 < 8192) ? N0 : 8192;    // 2 * 16^3

  char* wsb = (char*)d_ws;
  size_t off = 0;
  auto alloc = [&](size_t bytes) {
    char* p = wsb + off;
    off = (off + bytes + 255) & ~(size_t)255;
    return p;
  };
  float* stats = (float*)alloc(7 * 1024 * 4);
  int* base7 = (int*)alloc(6 * 32 * 4);
  int* invT = (int*)alloc((size_t)28 * N0 * 4);
  unsigned short* e1 = (unsigned short*)alloc((size_t)N0 * 32 * 2);
  unsigned short* e2 = (unsigned short*)alloc((size_t)N0 * 64 * 2);
  unsigned short* e3 = (unsigned short*)alloc((size_t)MAXN2 * 128 * 2);
  unsigned short* e4 = (unsigned short*)alloc((size_t)MAXN3 * 256 * 2);
  unsigned short* t4 = (unsigned short*)alloc((size_t)MAXN2 * 128 * 2);
  unsigned short* t3 = (unsigned short*)alloc((size_t)N0 * 64 * 2);
  unsigned short* t2 = (unsigned short*)alloc((size_t)N0 * 32 * 2);
  unsigned short* Wf2 = (unsigned short*)alloc((size_t)27 * 32 * 64 * 2);
  unsigned short* Wf3 = (unsigned short*)alloc((size_t)27 * 64 * 128 * 2);
  unsigned short* Wf4 = (unsigned short*)alloc((size_t)27 * 128 * 256 * 2);
  unsigned short* WfD4 = (unsigned short*)alloc((size_t)27 * 256 * 128 * 2);
  unsigned short* WfD3 = (unsigned short*)alloc((size_t)27 * 256 * 64 * 2);
  unsigned short* WfD2 = (unsigned short*)alloc((size_t)27 * 128 * 32 * 2);
  size_t cmax = (size_t)27 * P2 * 64;
  { size_t v;
    v = (size_t)27 * P3 * 128; if (v > cmax) cmax = v;
    v = (size_t)27 * P4 * 128; if (v > cmax) cmax = v;
    v = (size_t)27 * P3 * 64;  if (v > cmax) cmax = v;
    v = (size_t)27 * P2 * 32;  if (v > cmax) cmax = v; }
  unsigned short* contrib = (unsigned short*)alloc(cmax * 2);
  if (off > ws_size) return;  // loud fail if scratch too small

  hipMemsetAsync(stats, 0, 7 * 1024 * 4, stream);
  const dim3 blk(256);
#define ST(i) (stats + (i)*1024)
#define FGRID(n) dim3((unsigned)CDIV((long)(n) * 28, 256))

  // ---- batched weight prep ----
  {
    PrepArgs pa;
    pa.src[0] = W2;  pa.dst[0] = Wf2;  pa.cin[0] = 32;  pa.cout[0] = 64;
    pa.src[1] = W3;  pa.dst[1] = Wf3;  pa.cin[1] = 64;  pa.cout[1] = 128;
    pa.src[2] = W4;  pa.dst[2] = Wf4;  pa.cin[2] = 128; pa.cout[2] = 256;
    pa.src[3] = D4w; pa.dst[3] = WfD4; pa.cin[3] = 256; pa.cout[3] = 128;
    pa.src[4] = D3w; pa.dst[4] = WfD3; pa.cin[4] = 256; pa.cout[4] = 64;
    pa.src[5] = D2w; pa.dst[5] = WfD2; pa.cin[5] = 128; pa.cout[5] = 32;
    int acc = 0;
    for (int i = 0; i < 6; ++i) {
      pa.cstart[i] = acc;
      acc += 27 * (pa.cin[i] / 32) * (pa.cout[i] / 16);
    }
    pa.cstart[6] = acc;
    prep_all_k<<<CDIV(acc, 4), blk, 0, stream>>>(pa);
  }
  kmap_all_k<<<6, 32, 0, stream>>>(m2o, P2, n1d, m3o, P3, n2d, m4o, P4, n3d,
                                   m4i, m3i, m2i, N0, base7);

  // ---- conv1: 4->32, 4 threads/row ----
  fillT_k<<<FGRID(N0), blk, 0, stream>>>(invT, nullptr, N0);
  inv_build_k<<<dim3(CDIV(P1, 256), 27), blk, 0, stream>>>(m1i, m1o, P1, N0, invT);
  conv1_k<<<CDIV(N0 * 4, 256), blk, 0, stream>>>(feats, W1, invT, N0, e1);
  bn_stats_bf16_k<32><<<512, blk, 0, stream>>>(e1, nullptr, N0, ST(0));
  bn_apply_bf16_k<<<1024, blk, 0, stream>>>(e1, 4, ST(0), g1, b1, 32, nullptr, N0);

  // ---- conv2: 32->64 compact, ARM=4 ----
  fillT_k<<<FGRID(N0), blk, 0, stream>>>(invT, n1d, -1);
  inv_scatter_k<<<dim3(CDIV(P2, 256), 27), blk, 0, stream>>>(m2o, P2, base7 + 0 * 32, invT);
  pgemm_k<32, 0, 64, 1, 4><<<dim3(CDIV(P2, 256), 27), blk, 0, stream>>>(
      e1, nullptr, Wf2, m2i, P2, base7 + 0 * 32, contrib, 0, 64);
  reduce_bf16_k<64><<<CDIV(N0, 32), blk, 0, stream>>>(contrib, invT, n1d, -1, e2, 64, 0);
  bn_stats_bf16_k<64><<<512, blk, 0, stream>>>(e2, n1d, -1, ST(1));
  bn_apply_bf16_k<<<1024, blk, 0, stream>>>(e2, 8, ST(1), g2, b2, 64, n1d, -1);

  // ---- conv3: 64->128 compact ----
  fillT_k<<<FGRID(MAXN2), blk, 0, stream>>>(invT, n2d, -1);
  inv_scatter_k<<<dim3(CDIV(P3, 256), 27), blk, 0, stream>>>(m3o, P3, base7 + 1 * 32, invT);
  pgemm_k<64, 0, 128, 1, 2><<<dim3(CDIV(P3, 128), 27), blk, 0, stream>>>(
      e2, nullptr, Wf3, m3i, P3, base7 + 1 * 32, contrib, 0, 128);
  reduce_bf16_k<128><<<CDIV(MAXN2, 16), blk, 0, stream>>>(contrib, invT, n2d, -1, e3, 128, 0);
  bn_stats_bf16_k<128><<<512, blk, 0, stream>>>(e3, n2d, -1, ST(2));
  bn_apply_bf16_k<<<1024, blk, 0, stream>>>(e3, 16, ST(2), g3, b3, 128, n2d, -1);

  // ---- conv4: 128->256 compact, two column halves ----
  fillT_k<<<FGRID(MAXN3), blk, 0, stream>>>(invT, n3d, -1);
  inv_scatter_k<<<dim3(CDIV(P4, 256), 27), blk, 0, stream>>>(m4o, P4, base7 + 2 * 32, invT);
  for (int cb = 0; cb < 2; ++cb) {
    pgemm_k<128, 0, 256, 2, 2><<<dim3(CDIV(P4, 128), 27), blk, 0, stream>>>(
        e3, nullptr, Wf4, m4i, P4, base7 + 2 * 32, contrib, cb, 128);
    reduce_bf16_k<128><<<CDIV(MAXN3, 16), blk, 0, stream>>>(
        contrib, invT, n3d, -1, e4, 256, cb * 128);
  }
  bn_stats_bf16_k<256><<<512, blk, 0, stream>>>(e4, n3d, -1, ST(3));
  bn_apply_bf16_k<<<512, blk, 0, stream>>>(e4, 32, ST(3), g4, b4, 256, n3d, -1);

  // ---- D4: tconv 256->128 compact (maps swapped), unsplit ----
  fillT_k<<<FGRID(MAXN2), blk, 0, stream>>>(invT, n2d, -1);
  inv_scatter_k<<<dim3(CDIV(P4, 256), 27), blk, 0, stream>>>(m4i, P4, base7 + 3 * 32, invT);
  pgemm_k<256, 0, 128, 1, 2><<<dim3(CDIV(P4, 128), 27), blk, 0, stream>>>(
      e4, nullptr, WfD4, m4o, P4, base7 + 3 * 32, contrib, 0, 128);
  reduce_bf16_k<128><<<CDIV(MAXN2, 16), blk, 0, stream>>>(contrib, invT, n2d, -1, t4, 128, 0);
  bn_stats_bf16_k<128><<<512, blk, 0, stream>>>(t4, n2d, -1, ST(4));
  bn_apply_bf16_k<<<1024, blk, 0, stream>>>(t4, 16, ST(4), gd4, bd4, 128, n2d, -1);

  // ---- D3: tconv concat(t4,e3)=256 -> 64 compact ----
  fillT_k<<<FGRID(N0), blk, 0, stream>>>(invT, n1d, -1);
  inv_scatter_k<<<dim3(CDIV(P3, 256), 27), blk, 0, stream>>>(m3i, P3, base7 + 4 * 32, invT);
  pgemm_k<128, 128, 64, 1, 2><<<dim3(CDIV(P3, 128), 27), blk, 0, stream>>>(
      t4, e3, WfD3, m3o, P3, base7 + 4 * 32, contrib, 0, 64);
  reduce_bf16_k<64><<<CDIV(N0, 32), blk, 0, stream>>>(contrib, invT, n1d, -1, t3, 64, 0);
  bn_stats_bf16_k<64><<<512, blk, 0, stream>>>(t3, n1d, -1, ST(5));
  bn_apply_bf16_k<<<1024, blk, 0, stream>>>(t3, 8, ST(5), gd3, bd3, 64, n1d, -1);

  // ---- D2: tconv concat(t3,e2)=128 -> 32 compact (t2 BN folded into final) ----
  fillT_k<<<FGRID(N0), blk, 0, stream>>>(invT, nullptr, N0);
  inv_scatter_k<<<dim3(CDIV(P2, 256), 27), blk, 0, stream>>>(m2i, P2, base7 + 5 * 32, invT);
  pgemm_k<64, 64, 32, 1, 2><<<dim3(CDIV(P2, 128), 27), blk, 0, stream>>>(
      t3, e2, WfD2, m2o, P2, base7 + 5 * 32, contrib, 0, 32);
  reduce_bf16_k<32><<<CDIV(N0, 64), blk, 0, stream>>>(contrib, invT, nullptr, N0, t2, 32, 0);
  bn_stats_bf16_k<32><<<512, blk, 0, stream>>>(t2, nullptr, N0, ST(6));

  // ---- final 1x1 with fused t2 BN+ReLU ----
  final_gemm_k<<<CDIV(N0, 256), blk, 0, stream>>>(
      t2, e1, Wf, ST(6), gd2, bd2, (float*)d_out, N0);

#undef ST
#undef FGRID
}